// Round 5
// baseline (6059.888 us; speedup 1.0000x reference)
//
#include <hip/hip_runtime.h>
#include <math.h>

// Problem constants
#define BN   128      // batch
#define TN   1440     // timesteps
#define HN   512      // hidden
#define GBn  8        // batch groups
#define BSn  16       // batches per group
#define GCn  32       // column groups
#define HCn  16       // h-cols per WG
#define WST  536      // LDS row stride in f16: 268 dw == 12 mod 32 -> conflict-free b128 frag reads
#define FLSTR 32      // flag stride in ints (128 B): one L2/L3 line per flag

using f16 = _Float16;
typedef f16   f16x8 __attribute__((ext_vector_type(8)));
typedef float f32x4 __attribute__((ext_vector_type(4)));
typedef unsigned int       uint32;
typedef unsigned long long u64;

// ws layout (bytes):
//   [0,32768)            flags int [8 gb][32 gc], stride 32 ints (one 128B line each)
//   [32768,33792)        scal: [0]=half_tau, [1]=trigger
//   [33792,1082368)      hbuf u64 [2 buf][128 b][512 k]
//                          lo32 = packed payload (lo16=f16 hi, hi16=f16 lo*2048)
//                          hi32 = tag: h-step index (producer at step t stores tag t+1;
//                                 memset-0 == "h_0 = 0 ready")
//   [1082368,1819648)    xsf f32 [128][1440]
#define OFF_SCAL 32768
#define OFF_HBUF 33792
#define OFF_XSF  (OFF_HBUF + 2 * BN * HN * 8)

// ---------------- K0: scalar prep (grads -> half_tau, trigger) ----------------
__global__ void k_prep(const float* __restrict__ w_ih, float* __restrict__ scal) {
    __shared__ float ssum[4];
    float s = 0.0f;
    for (int i = threadIdx.x; i < 3 * HN * 2; i += 256) s += w_ih[i];
    for (int o = 32; o >= 1; o >>= 1) s += __shfl_down(s, o, 64);
    if ((threadIdx.x & 63) == 0) ssum[threadIdx.x >> 6] = s;
    __syncthreads();
    if (threadIdx.x == 0) {
        float tot = ssum[0] + ssum[1] + ssum[2] + ssum[3];
        float grads = tot / 3072.0f - 1.0f;
        float tau_new = 6.0f + grads * 0.1f;
        bool trig = (tau_new >= 1.0f) && (tau_new != 6.0f);
        scal[0] = rintf(tau_new * 0.5f);   // round-half-even matches jnp.round
        scal[1] = trig ? 1.0f : 0.0f;
    }
}

// ---------------- K1: NaN-fix + belief_fill (one wave per batch row) ----------------
__global__ void k_fill(const float* __restrict__ inp, const float* __restrict__ scal,
                       float* __restrict__ xsf) {
    const int b = blockIdx.x;
    const int lane = threadIdx.x;            // 0..63
    const float ht = scal[0];
    const bool trig = scal[1] != 0.0f;
    const float* xrow = inp + (size_t)b * 3 * TN;       // channel 0 = xs
    const float* mrow = xrow + 2 * TN;                   // channel 2 = mask
    const int CH = 23;                                   // 64*23 = 1472 >= 1440
    const int start = lane * CH;

    if (!trig) {
        for (int i = 0; i < CH; ++i) {
            int t = start + i;
            if (t < TN) { float x = xrow[t]; if (x != x) x = -1.0f; xsf[(size_t)b * TN + t] = x; }
        }
        return;
    }
    int pm = -1;
#pragma unroll
    for (int i = 0; i < CH; ++i) { int t = start + i; if (t < TN && mrow[t] == 1.0f) pm = t; }
    int incl = pm;
    for (int o = 1; o < 64; o <<= 1) { int v = __shfl_up(incl, o, 64); if (lane >= o) incl = max(incl, v); }
    int pexcl = __shfl_up(incl, 1, 64); if (lane == 0) pexcl = -1;
    int nm = TN;
#pragma unroll
    for (int i = CH - 1; i >= 0; --i) { int t = start + i; if (t < TN && mrow[t] == 1.0f) nm = t; }
    int incl2 = nm;
    for (int o = 1; o < 64; o <<= 1) { int v = __shfl_down(incl2, o, 64); if (lane + o < 64) incl2 = min(incl2, v); }
    int nexcl = __shfl_down(incl2, 1, 64); if (lane == 63) nexcl = TN;
    int narr[23];
    int runn = nexcl;
#pragma unroll
    for (int i = CH - 1; i >= 0; --i) {
        int t = start + i;
        if (t < TN) { if (mrow[t] == 1.0f) runn = t; narr[i] = runn; } else narr[i] = TN;
    }
    int runp = pexcl;
#pragma unroll
    for (int i = 0; i < CH; ++i) {
        int t = start + i;
        if (t >= TN) break;
        float x = xrow[t]; if (x != x) x = -1.0f;
        if (mrow[t] == 1.0f) runp = t;
        int pv = runp, nv = narr[i];
        int pc = min(max(pv, 0), TN - 1), nc = min(max(nv, 0), TN - 1);
        float xp = xrow[pc]; if (xp != xp) xp = -1.0f;
        float xn = xrow[nc]; if (xn != xn) xn = -1.0f;
        bool use_n = (nv < TN) && ((float)t >= (float)nv - ht);
        bool use_p = (pv >= 0) && ((float)t <= (float)pv + ht);
        float o = use_n ? xn : (use_p ? xp : x);
        xsf[(size_t)b * TN + t] = o;
    }
}

// ---------------- K2: persistent column-split GRU, L3-coherent comm ----------------
// grid 256 = 8 batch-groups x 32 col-groups; block 256 (4 waves); 1 WG/CU.
// R0's proven agent-scope protocol with ONE change: each h element is a tagged
// {payload,tag} u64 (single 8B relaxed atomic store, architecturally single-copy
// atomic), so the flag no longer certifies data validity -- it is only a discovery
// hint. This lets the pre-flag barrier drop its vmcnt(0) drain (the ~900cy L3 store-ack
// on the critical path): raw s_barrier + lgkmcnt(0) proves all 256 publish stores were
// ISSUED before tid0's flag store; per-element tag checks repair the rare straggler
// (a store has >=1.5 L3 RTTs to land before any post-discovery load is served).
// Discovery itself stays byte-for-byte R0 (relaxed agent flag poll; padded flag lines).
// ABA/parity: WG A can publish tag t+2 into a parity slot only after consuming ALL
// tag-t+1 data, which requires every WG published t+1, which requires every WG consumed
// tag t -- so no slot a consumer still needs can be overwritten. Both parity buffers
// are memset each launch (graph-replay stale-tag safety). G16-safe: no placement
// assumptions, agent-scope everywhere.
__global__ __launch_bounds__(256, 1) void k_gru(
    const float* __restrict__ inp, const float* __restrict__ w_ih,
    const float* __restrict__ w_hh, const float* __restrict__ b_ih,
    const float* __restrict__ b_hh, const float* __restrict__ w_fc,
    const float* __restrict__ b_fc, const float* __restrict__ xsf,
    u64* __restrict__ hbuf, int* __restrict__ flags, float* __restrict__ out) {
    __shared__ __align__(16) f16 sHhi[BSn * WST];
    __shared__ __align__(16) f16 sHlo[BSn * WST];
    __shared__ float sGh[3][BSn][HCn + 1];
    __shared__ float sWi0[48], sWi1[48], sBias[48];

    const int tid = threadIdx.x;
    const int gb = blockIdx.x & 7;
    const int gc = blockIdx.x >> 3;
    const int lane = tid & 63;
    const int wv   = tid >> 6;
    const int bs   = tid >> 4;        // gate-math row 0..15
    const int j    = tid & 15;
    const int bglob = gb * BSn + bs;
    const int pcol  = gc * HCn + j;
    const int frow = lane & 15;       // MFMA m (A) / n (B) index
    const int kgrp = lane >> 4;       // MFMA k-group

    if (tid < 48) {
        int gate = tid >> 4, jj = tid & 15;
        int grow = gate * HN + gc * HCn + jj;
        sWi0[tid]  = w_ih[grow * 2 + 0];
        sWi1[tid]  = w_ih[grow * 2 + 1];
        sBias[tid] = b_ih[grow] + b_hh[grow];
    }

    // one-time: weight B-fragments into VGPRs (hi + lo*2^11 split)
    f16x8 bfh[16], bfl[16];
    if (wv < 3) {
        const float* wrow = w_hh + (size_t)(wv * HN + gc * HCn + frow) * HN;
#pragma unroll
        for (int c = 0; c < 16; ++c) {
            const int k0 = (c * 4 + kgrp) * 8;
#pragma unroll
            for (int u = 0; u < 8; ++u) {
                float w = wrow[k0 + u];
                f16 hi = (f16)w;
                bfh[c][u] = hi;
                bfl[c][u] = (f16)((w - (float)hi) * 2048.0f);
            }
        }
    }
    __syncthreads();

    int* myflags = flags + gb * GCn * FLSTR;
    const f16x8* pAhi = (const f16x8*)(sHhi + frow * WST);
    const f16x8* pAlo = (const f16x8*)(sHlo + frow * WST);
    float h = 0.0f;

    for (int t = 0; t < TN; ++t) {
        // prefetch driving inputs (independent of sync)
        float xsv = xsf[(size_t)bglob * TN + t];
        float mkv = inp[((size_t)bglob * 3 + 2) * TN + t];
        const u64* src = hbuf + ((size_t)(t & 1) * BN + gb * BSn) * HN;

        // 1. every wave polls all 32 peer flags (relaxed agent load = L3 read)
        if (lane < GCn) {
            while (__hip_atomic_load(&myflags[lane * FLSTR], __ATOMIC_RELAXED,
                                     __HIP_MEMORY_SCOPE_AGENT) < t) {}
        }

        // 2. bulk h load: rows 0..15, cols {2*tid, 2*tid+1} -- 32 coalesced 8B atomic
        //    loads (64 lanes x 8B = 512B/instr), then tag-validate + repair (rare)
        u64 hA[16], hB[16];
#pragma unroll
        for (int i = 0; i < 16; ++i) {
            hA[i] = __hip_atomic_load(src + (size_t)i * HN + 2 * tid,
                                      __ATOMIC_RELAXED, __HIP_MEMORY_SCOPE_AGENT);
            hB[i] = __hip_atomic_load(src + (size_t)i * HN + 2 * tid + 1,
                                      __ATOMIC_RELAXED, __HIP_MEMORY_SCOPE_AGENT);
        }
#pragma unroll
        for (int i = 0; i < 16; ++i) {
            while ((uint32)(hA[i] >> 32) != (uint32)t)
                hA[i] = __hip_atomic_load(src + (size_t)i * HN + 2 * tid,
                                          __ATOMIC_RELAXED, __HIP_MEMORY_SCOPE_AGENT);
            while ((uint32)(hB[i] >> 32) != (uint32)t)
                hB[i] = __hip_atomic_load(src + (size_t)i * HN + 2 * tid + 1,
                                          __ATOMIC_RELAXED, __HIP_MEMORY_SCOPE_AGENT);
        }

        // 3. stage h_t into LDS (hi/lo deinterleave of the two payloads via v_perm)
#pragma unroll
        for (int i = 0; i < 16; ++i) {
            uint32 d0 = (uint32)hA[i], d1 = (uint32)hB[i];
            ((uint32*)(sHhi + i * WST))[tid] = __builtin_amdgcn_perm(d1, d0, 0x05040100u);
            ((uint32*)(sHlo + i * WST))[tid] = __builtin_amdgcn_perm(d1, d0, 0x07060302u);
        }
        __syncthreads();
        // 4. MFMA: wave wv computes gate tile wv (16x16), K=512, 3 split terms
        if (wv < 3) {
            f32x4 acch = {0.f, 0.f, 0.f, 0.f}, accl = {0.f, 0.f, 0.f, 0.f};
#pragma unroll
            for (int c = 0; c < 16; ++c) {
                f16x8 ah = pAhi[c * 4 + kgrp];
                f16x8 al = pAlo[c * 4 + kgrp];
                acch = __builtin_amdgcn_mfma_f32_16x16x32_f16(ah, bfh[c], acch, 0, 0, 0);
                accl = __builtin_amdgcn_mfma_f32_16x16x32_f16(ah, bfl[c], accl, 0, 0, 0);
                accl = __builtin_amdgcn_mfma_f32_16x16x32_f16(al, bfh[c], accl, 0, 0, 0);
            }
            // C/D: row=(lane>>4)*4+r (batch), col=lane&15 (j)
#pragma unroll
            for (int r = 0; r < 4; ++r)
                sGh[wv][kgrp * 4 + r][frow] = acch[r] + accl[r] * (1.0f / 2048.0f);
        }
        __syncthreads();
        // 5. exact fp32 gate math + tagged publish (8B relaxed atomic store, NO drain)
        {
            float ghr = sGh[0][bs][j], ghz = sGh[1][bs][j], ghn = sGh[2][bs][j];
            float gir = xsv * sWi0[j]      + mkv * sWi1[j]      + sBias[j];
            float giz = xsv * sWi0[16 + j] + mkv * sWi1[16 + j] + sBias[16 + j];
            float gin = xsv * sWi0[32 + j] + mkv * sWi1[32 + j] + sBias[32 + j];
            float rg = 1.0f / (1.0f + __expf(-(gir + ghr)));
            float zg = 1.0f / (1.0f + __expf(-(giz + ghz)));
            float ng = tanhf(gin + rg * ghn);
            h = (1.0f - zg) * ng + zg * h;
            f16 hi = (f16)h;
            f16 lo = (f16)((h - (float)hi) * 2048.0f);
            uint32 pk = (uint32)__builtin_bit_cast(unsigned short, hi)
                      | ((uint32)__builtin_bit_cast(unsigned short, lo) << 16);
            u64 val = (u64)pk | ((u64)(uint32)(t + 1) << 32);
            __hip_atomic_store(&hbuf[((size_t)((t + 1) & 1) * BN + bglob) * HN + pcol], val,
                               __ATOMIC_RELAXED, __HIP_MEMORY_SCOPE_AGENT);
        }
        // barrier WITHOUT vmem drain: arrival proves all publish stores are issued;
        // lgkmcnt(0) keeps LDS ordering (sGh reads done before next iter's overwrites).
        asm volatile("s_waitcnt lgkmcnt(0)" ::: "memory");
        __builtin_amdgcn_s_barrier();
        asm volatile("" ::: "memory");   // pin the flag store below the barrier
        if (tid == 0)
            __hip_atomic_store(&myflags[gc * FLSTR], t + 1, __ATOMIC_RELAXED,
                               __HIP_MEMORY_SCOPE_AGENT);
    }
    // 6. final FC: out[b] = sum_k h[b][k]*w_fc[k] + b_fc
    float part = h * w_fc[pcol];
#pragma unroll
    for (int o = 1; o < 16; o <<= 1) part += __shfl_xor(part, o, 64);
    if (j == 0) {
        if (gc == 0) part += b_fc[0];
        atomicAdd(&out[bglob], part);
    }
}

extern "C" void kernel_launch(void* const* d_in, const int* in_sizes, int n_in,
                              void* d_out, int out_size, void* d_ws, size_t ws_size,
                              hipStream_t stream) {
    const float* inp  = (const float*)d_in[0];
    const float* w_ih = (const float*)d_in[1];
    const float* w_hh = (const float*)d_in[2];
    const float* b_ih = (const float*)d_in[3];
    const float* b_hh = (const float*)d_in[4];
    const float* w_fc = (const float*)d_in[5];
    const float* b_fc = (const float*)d_in[6];
    float* out = (float*)d_out;
    char* ws = (char*)d_ws;
    int*    flags = (int*)ws;
    float*  scal  = (float*)(ws + OFF_SCAL);
    u64*    hbuf  = (u64*)(ws + OFF_HBUF);
    float*  xsf   = (float*)(ws + OFF_XSF);

    // zero: flags + scal + BOTH tagged h parity buffers (tag 0 == "h_0 = 0 ready";
    // stale tags from a previous graph replay must be cleared); d_out (atomicAdd target)
    hipMemsetAsync(ws, 0, OFF_HBUF + 2 * BN * HN * 8, stream);
    hipMemsetAsync(d_out, 0, BN * sizeof(float), stream);
    k_prep<<<1, 256, 0, stream>>>(w_ih, scal);
    k_fill<<<BN, 64, 0, stream>>>(inp, scal, xsf);
    k_gru<<<GBn * GCn, 256, 0, stream>>>(inp, w_ih, w_hh, b_ih, b_hh, w_fc, b_fc,
                                         xsf, hbuf, flags, out);
}

// Round 6
// 5298.180 us; speedup vs baseline: 1.1438x; 1.1438x over previous
//
#include <hip/hip_runtime.h>
#include <math.h>

// Problem constants
#define BN   128      // batch
#define TN   1440     // timesteps
#define HN   512      // hidden
#define GBn  8        // batch groups
#define BSn  16       // batches per group
#define GCn  32       // column groups
#define HCn  16       // h-cols per WG
#define WST  536      // LDS row stride in f16: 268 dw == 12 mod 32 -> conflict-free b128 frag reads
#define FLSTR 32      // flag stride in ints (128 B): one cache line per flag

using f16 = _Float16;
typedef f16   f16x8 __attribute__((ext_vector_type(8)));
typedef float f32x4 __attribute__((ext_vector_type(4)));
typedef unsigned int       uint32;
typedef unsigned long long u64;

// ws layout (bytes):
//   [0,32768)            flags int [8 gb][32 gc], stride 32 ints (one 128B line each)
//   [32768,33792)        scal: [0]=half_tau, [1]=trigger
//   [33792,558080)       hbufP uint32 [2 buf][128 b][512 k] (lo16=f16 hi, hi16=f16 lo*2048)
//   [558080,1295360)     xsf f32 [128][1440]
#define OFF_SCAL 32768
#define OFF_HBUF 33792
#define OFF_XSF  (OFF_HBUF + 2 * BN * HN * 4)

// ---------------- K0: scalar prep (grads -> half_tau, trigger) ----------------
__global__ void k_prep(const float* __restrict__ w_ih, float* __restrict__ scal) {
    __shared__ float ssum[4];
    float s = 0.0f;
    for (int i = threadIdx.x; i < 3 * HN * 2; i += 256) s += w_ih[i];
    for (int o = 32; o >= 1; o >>= 1) s += __shfl_down(s, o, 64);
    if ((threadIdx.x & 63) == 0) ssum[threadIdx.x >> 6] = s;
    __syncthreads();
    if (threadIdx.x == 0) {
        float tot = ssum[0] + ssum[1] + ssum[2] + ssum[3];
        float grads = tot / 3072.0f - 1.0f;
        float tau_new = 6.0f + grads * 0.1f;
        bool trig = (tau_new >= 1.0f) && (tau_new != 6.0f);
        scal[0] = rintf(tau_new * 0.5f);   // round-half-even matches jnp.round
        scal[1] = trig ? 1.0f : 0.0f;
    }
}

// ---------------- K1: NaN-fix + belief_fill (one wave per batch row) ----------------
__global__ void k_fill(const float* __restrict__ inp, const float* __restrict__ scal,
                       float* __restrict__ xsf) {
    const int b = blockIdx.x;
    const int lane = threadIdx.x;            // 0..63
    const float ht = scal[0];
    const bool trig = scal[1] != 0.0f;
    const float* xrow = inp + (size_t)b * 3 * TN;       // channel 0 = xs
    const float* mrow = xrow + 2 * TN;                   // channel 2 = mask
    const int CH = 23;                                   // 64*23 = 1472 >= 1440
    const int start = lane * CH;

    if (!trig) {
        for (int i = 0; i < CH; ++i) {
            int t = start + i;
            if (t < TN) { float x = xrow[t]; if (x != x) x = -1.0f; xsf[(size_t)b * TN + t] = x; }
        }
        return;
    }
    int pm = -1;
#pragma unroll
    for (int i = 0; i < CH; ++i) { int t = start + i; if (t < TN && mrow[t] == 1.0f) pm = t; }
    int incl = pm;
    for (int o = 1; o < 64; o <<= 1) { int v = __shfl_up(incl, o, 64); if (lane >= o) incl = max(incl, v); }
    int pexcl = __shfl_up(incl, 1, 64); if (lane == 0) pexcl = -1;
    int nm = TN;
#pragma unroll
    for (int i = CH - 1; i >= 0; --i) { int t = start + i; if (t < TN && mrow[t] == 1.0f) nm = t; }
    int incl2 = nm;
    for (int o = 1; o < 64; o <<= 1) { int v = __shfl_down(incl2, o, 64); if (lane + o < 64) incl2 = min(incl2, v); }
    int nexcl = __shfl_down(incl2, 1, 64); if (lane == 63) nexcl = TN;
    int narr[23];
    int runn = nexcl;
#pragma unroll
    for (int i = CH - 1; i >= 0; --i) {
        int t = start + i;
        if (t < TN) { if (mrow[t] == 1.0f) runn = t; narr[i] = runn; } else narr[i] = TN;
    }
    int runp = pexcl;
#pragma unroll
    for (int i = 0; i < CH; ++i) {
        int t = start + i;
        if (t >= TN) break;
        float x = xrow[t]; if (x != x) x = -1.0f;
        if (mrow[t] == 1.0f) runp = t;
        int pv = runp, nv = narr[i];
        int pc = min(max(pv, 0), TN - 1), nc = min(max(nv, 0), TN - 1);
        float xp = xrow[pc]; if (xp != xp) xp = -1.0f;
        float xn = xrow[nc]; if (xn != xn) xn = -1.0f;
        bool use_n = (nv < TN) && ((float)t >= (float)nv - ht);
        bool use_p = (pv >= 0) && ((float)t <= (float)pv + ht);
        float o = use_n ? xn : (use_p ? xp : x);
        xsf[(size_t)b * TN + t] = o;
    }
}

// ---------------- K2: persistent column-split GRU, L3-coherent comm ----------------
// grid 256 = 8 batch-groups x 32 col-groups; block 256 (4 waves); 1 WG/CU.
// Protocol is byte-for-byte the proven R0 scheme: relaxed agent-scope atomics only,
// per-WG flags, producer __syncthreads drains vmcnt(0) (stores acked at coherence
// point) before the tid0 flag store. G16-safe, no placement assumptions.
// R6 latency tuning on top (protocol untouched):
//  - flags padded to one 128B line each (32 writers + all pollers no longer share
//    2 hot cache lines -> cheaper flag store AND poll RTT)
//  - speculative L2-warming prefetch of the full h-block BEFORE the poll: producers'
//    probe-invalidated lines get re-filled into the local L2 during the poll window,
//    so the flag-gated real load L2-hits instead of missing to fabric. Prefetched
//    values are DISCARDED (keep-alive only) -> zero correctness impact.
//  - one-time per-gb start stagger de-phases the 8 independent rings' fabric bursts.
__global__ __launch_bounds__(256, 1) void k_gru(
    const float* __restrict__ inp, const float* __restrict__ w_ih,
    const float* __restrict__ w_hh, const float* __restrict__ b_ih,
    const float* __restrict__ b_hh, const float* __restrict__ w_fc,
    const float* __restrict__ b_fc, const float* __restrict__ xsf,
    uint32* __restrict__ hbufP, int* __restrict__ flags, float* __restrict__ out) {
    __shared__ __align__(16) f16 sHhi[BSn * WST];
    __shared__ __align__(16) f16 sHlo[BSn * WST];
    __shared__ float sGh[3][BSn][HCn + 1];
    __shared__ float sWi0[48], sWi1[48], sBias[48];

    const int tid = threadIdx.x;
    const int gb = blockIdx.x & 7;
    const int gc = blockIdx.x >> 3;
    const int lane = tid & 63;
    const int wv   = tid >> 6;
    const int bs   = tid >> 4;        // gate-math row 0..15
    const int j    = tid & 15;
    const int bglob = gb * BSn + bs;
    const int pcol  = gc * HCn + j;
    const int frow = lane & 15;       // MFMA m (A) / n (B) index
    const int kgrp = lane >> 4;       // MFMA k-group

    if (tid < 48) {
        int gate = tid >> 4, jj = tid & 15;
        int grow = gate * HN + gc * HCn + jj;
        sWi0[tid]  = w_ih[grow * 2 + 0];
        sWi1[tid]  = w_ih[grow * 2 + 1];
        sBias[tid] = b_ih[grow] + b_hh[grow];
    }

    // one-time: weight B-fragments into VGPRs (hi + lo*2^11 split)
    f16x8 bfh[16], bfl[16];
    if (wv < 3) {
        const float* wrow = w_hh + (size_t)(wv * HN + gc * HCn + frow) * HN;
#pragma unroll
        for (int c = 0; c < 16; ++c) {
            const int k0 = (c * 4 + kgrp) * 8;
#pragma unroll
            for (int u = 0; u < 8; ++u) {
                float w = wrow[k0 + u];
                f16 hi = (f16)w;
                bfh[c][u] = hi;
                bfl[c][u] = (f16)((w - (float)hi) * 2048.0f);
            }
        }
    }
    __syncthreads();

    // one-time stagger: de-phase the 8 independent batch-group rings (~1k cy per gb)
    for (int s = 0; s < gb * 2; ++s) __builtin_amdgcn_s_sleep(8);

    int* myflags = flags + gb * GCn * FLSTR;
    const f16x8* pAhi = (const f16x8*)(sHhi + frow * WST);
    const f16x8* pAlo = (const f16x8*)(sHlo + frow * WST);
    float h = 0.0f;

    for (int t = 0; t < TN; ++t) {
        // prefetch driving inputs (independent of sync)
        float xsv = xsf[(size_t)bglob * TN + t];
        float mkv = inp[((size_t)bglob * 3 + 2) * TN + t];
        const uint32* src = hbufP + ((size_t)(t & 1) * BN + gb * BSn) * HN;

        // 0. speculative L2-warming prefetch of the h-block (values DISCARDED; the
        //    flag-gated reload below is the only data consumed). Fills the local L2
        //    during the poll window so the real load L2-hits.
        u64 pfv[16];
#pragma unroll
        for (int i = 0; i < 16; ++i)
            pfv[i] = __hip_atomic_load((const u64*)(src + (size_t)i * HN) + tid,
                                       __ATOMIC_RELAXED, __HIP_MEMORY_SCOPE_AGENT);

        // 1. every wave polls all 32 peer flags (relaxed atomic load, padded lines)
        if (lane < GCn) {
            while (__hip_atomic_load(&myflags[lane * FLSTR], __ATOMIC_RELAXED,
                                     __HIP_MEMORY_SCOPE_AGENT) < t) {}
        }

        // 2. real (flag-gated) h load: 16 coherent u64 loads/thread
        u64 hv[16];
#pragma unroll
        for (int i = 0; i < 16; ++i)
            hv[i] = __hip_atomic_load((const u64*)(src + (size_t)i * HN) + tid,
                                      __ATOMIC_RELAXED, __HIP_MEMORY_SCOPE_AGENT);

        // keep the prefetch live without consuming it (DCE guard, rule #17)
        {
            u64 acc = 0;
#pragma unroll
            for (int i = 0; i < 16; ++i) acc ^= pfv[i];
            asm volatile("" :: "v"(acc));
        }

        // 3. stage h_t into LDS (hi/lo byte-deinterleave via v_perm)
#pragma unroll
        for (int i = 0; i < 16; ++i) {
            uint32 d0 = (uint32)hv[i], d1 = (uint32)(hv[i] >> 32);
            ((uint32*)(sHhi + i * WST))[tid] = __builtin_amdgcn_perm(d1, d0, 0x05040100u);
            ((uint32*)(sHlo + i * WST))[tid] = __builtin_amdgcn_perm(d1, d0, 0x07060302u);
        }
        __syncthreads();
        // 4. MFMA: wave wv computes gate tile wv (16x16), K=512, 3 split terms
        if (wv < 3) {
            f32x4 acch = {0.f, 0.f, 0.f, 0.f}, accl = {0.f, 0.f, 0.f, 0.f};
#pragma unroll
            for (int c = 0; c < 16; ++c) {
                f16x8 ah = pAhi[c * 4 + kgrp];
                f16x8 al = pAlo[c * 4 + kgrp];
                acch = __builtin_amdgcn_mfma_f32_16x16x32_f16(ah, bfh[c], acch, 0, 0, 0);
                accl = __builtin_amdgcn_mfma_f32_16x16x32_f16(ah, bfl[c], accl, 0, 0, 0);
                accl = __builtin_amdgcn_mfma_f32_16x16x32_f16(al, bfh[c], accl, 0, 0, 0);
            }
            // C/D: row=(lane>>4)*4+r (batch), col=lane&15 (j)
#pragma unroll
            for (int r = 0; r < 4; ++r)
                sGh[wv][kgrp * 4 + r][frow] = acch[r] + accl[r] * (1.0f / 2048.0f);
        }
        __syncthreads();
        // 5. exact fp32 gate math + publish h_{t+1} slice (write-through atomic store)
        {
            float ghr = sGh[0][bs][j], ghz = sGh[1][bs][j], ghn = sGh[2][bs][j];
            float gir = xsv * sWi0[j]      + mkv * sWi1[j]      + sBias[j];
            float giz = xsv * sWi0[16 + j] + mkv * sWi1[16 + j] + sBias[16 + j];
            float gin = xsv * sWi0[32 + j] + mkv * sWi1[32 + j] + sBias[32 + j];
            float rg = 1.0f / (1.0f + __expf(-(gir + ghr)));
            float zg = 1.0f / (1.0f + __expf(-(giz + ghz)));
            float ng = tanhf(gin + rg * ghn);
            h = (1.0f - zg) * ng + zg * h;
            f16 hi = (f16)h;
            f16 lo = (f16)((h - (float)hi) * 2048.0f);
            uint32 pk = (uint32)__builtin_bit_cast(unsigned short, hi)
                      | ((uint32)__builtin_bit_cast(unsigned short, lo) << 16);
            __hip_atomic_store(&hbufP[((size_t)((t + 1) & 1) * BN + bglob) * HN + pcol], pk,
                               __ATOMIC_RELAXED, __HIP_MEMORY_SCOPE_AGENT);
        }
        __syncthreads();   // compiler drains vmcnt(0) before s_barrier -> publishes acked
        if (tid == 0)
            __hip_atomic_store(&myflags[gc * FLSTR], t + 1, __ATOMIC_RELAXED,
                               __HIP_MEMORY_SCOPE_AGENT);
    }
    // 6. final FC: out[b] = sum_k h[b][k]*w_fc[k] + b_fc
    float part = h * w_fc[pcol];
#pragma unroll
    for (int o = 1; o < 16; o <<= 1) part += __shfl_xor(part, o, 64);
    if (j == 0) {
        if (gc == 0) part += b_fc[0];
        atomicAdd(&out[bglob], part);
    }
}

extern "C" void kernel_launch(void* const* d_in, const int* in_sizes, int n_in,
                              void* d_out, int out_size, void* d_ws, size_t ws_size,
                              hipStream_t stream) {
    const float* inp  = (const float*)d_in[0];
    const float* w_ih = (const float*)d_in[1];
    const float* w_hh = (const float*)d_in[2];
    const float* b_ih = (const float*)d_in[3];
    const float* b_hh = (const float*)d_in[4];
    const float* w_fc = (const float*)d_in[5];
    const float* b_fc = (const float*)d_in[6];
    float* out = (float*)d_out;
    char* ws = (char*)d_ws;
    int*    flags = (int*)ws;
    float*  scal  = (float*)(ws + OFF_SCAL);
    uint32* hbufP = (uint32*)(ws + OFF_HBUF);
    float*  xsf   = (float*)(ws + OFF_XSF);

    // zero: flags + scal + packed-h buf0 (= h_0 = 0); d_out (atomicAdd target)
    hipMemsetAsync(ws, 0, OFF_HBUF + BN * HN * 4, stream);
    hipMemsetAsync(d_out, 0, BN * sizeof(float), stream);
    k_prep<<<1, 256, 0, stream>>>(w_ih, scal);
    k_fill<<<BN, 64, 0, stream>>>(inp, scal, xsf);
    k_gru<<<GBn * GCn, 256, 0, stream>>>(inp, w_ih, w_hh, b_ih, b_hh, w_fc, b_fc,
                                         xsf, hbufP, flags, out);
}

// Round 7
// 5153.002 us; speedup vs baseline: 1.1760x; 1.0282x over previous
//
#include <hip/hip_runtime.h>
#include <math.h>

// Problem constants
#define BN   128      // batch
#define TN   1440     // timesteps
#define HN   512      // hidden
#define GBn  8        // batch groups
#define BSn  16       // batches per group
#define GCn  32       // column groups
#define HCn  16       // h-cols per WG
#define FLSTR 32      // flag stride in ints (128 B): one cache line per flag

using f16 = _Float16;
typedef f16   f16x8 __attribute__((ext_vector_type(8)));
typedef float f32x4 __attribute__((ext_vector_type(4)));
typedef unsigned int       uint32;
typedef uint32 u32x4 __attribute__((ext_vector_type(4)));
typedef unsigned long long u64;

// ws layout (bytes):
//   [0,32768)            flags int [8 gb][32 gc], stride 32 ints (one 128B line each)
//   [32768,33792)        scal: [0]=half_tau, [1]=trigger
//   [33792,558080)       hbufP uint32 [2 buf][128 b][512 k] (lo16=f16 hi, hi16=f16 lo*2048)
//   [558080,1295360)     xsf f32 [128][1440]
#define OFF_SCAL 32768
#define OFF_HBUF 33792
#define OFF_XSF  (OFF_HBUF + 2 * BN * HN * 4)

// ---------------- K0: scalar prep (grads -> half_tau, trigger) ----------------
__global__ void k_prep(const float* __restrict__ w_ih, float* __restrict__ scal) {
    __shared__ float ssum[4];
    float s = 0.0f;
    for (int i = threadIdx.x; i < 3 * HN * 2; i += 256) s += w_ih[i];
    for (int o = 32; o >= 1; o >>= 1) s += __shfl_down(s, o, 64);
    if ((threadIdx.x & 63) == 0) ssum[threadIdx.x >> 6] = s;
    __syncthreads();
    if (threadIdx.x == 0) {
        float tot = ssum[0] + ssum[1] + ssum[2] + ssum[3];
        float grads = tot / 3072.0f - 1.0f;
        float tau_new = 6.0f + grads * 0.1f;
        bool trig = (tau_new >= 1.0f) && (tau_new != 6.0f);
        scal[0] = rintf(tau_new * 0.5f);   // round-half-even matches jnp.round
        scal[1] = trig ? 1.0f : 0.0f;
    }
}

// ---------------- K1: NaN-fix + belief_fill (one wave per batch row) ----------------
__global__ void k_fill(const float* __restrict__ inp, const float* __restrict__ scal,
                       float* __restrict__ xsf) {
    const int b = blockIdx.x;
    const int lane = threadIdx.x;            // 0..63
    const float ht = scal[0];
    const bool trig = scal[1] != 0.0f;
    const float* xrow = inp + (size_t)b * 3 * TN;       // channel 0 = xs
    const float* mrow = xrow + 2 * TN;                   // channel 2 = mask
    const int CH = 23;                                   // 64*23 = 1472 >= 1440
    const int start = lane * CH;

    if (!trig) {
        for (int i = 0; i < CH; ++i) {
            int t = start + i;
            if (t < TN) { float x = xrow[t]; if (x != x) x = -1.0f; xsf[(size_t)b * TN + t] = x; }
        }
        return;
    }
    int pm = -1;
#pragma unroll
    for (int i = 0; i < CH; ++i) { int t = start + i; if (t < TN && mrow[t] == 1.0f) pm = t; }
    int incl = pm;
    for (int o = 1; o < 64; o <<= 1) { int v = __shfl_up(incl, o, 64); if (lane >= o) incl = max(incl, v); }
    int pexcl = __shfl_up(incl, 1, 64); if (lane == 0) pexcl = -1;
    int nm = TN;
#pragma unroll
    for (int i = CH - 1; i >= 0; --i) { int t = start + i; if (t < TN && mrow[t] == 1.0f) nm = t; }
    int incl2 = nm;
    for (int o = 1; o < 64; o <<= 1) { int v = __shfl_down(incl2, o, 64); if (lane + o < 64) incl2 = min(incl2, v); }
    int nexcl = __shfl_down(incl2, 1, 64); if (lane == 63) nexcl = TN;
    int narr[23];
    int runn = nexcl;
#pragma unroll
    for (int i = CH - 1; i >= 0; --i) {
        int t = start + i;
        if (t < TN) { if (mrow[t] == 1.0f) runn = t; narr[i] = runn; } else narr[i] = TN;
    }
    int runp = pexcl;
#pragma unroll
    for (int i = 0; i < CH; ++i) {
        int t = start + i;
        if (t >= TN) break;
        float x = xrow[t]; if (x != x) x = -1.0f;
        if (mrow[t] == 1.0f) runp = t;
        int pv = runp, nv = narr[i];
        int pc = min(max(pv, 0), TN - 1), nc = min(max(nv, 0), TN - 1);
        float xp = xrow[pc]; if (xp != xp) xp = -1.0f;
        float xn = xrow[nc]; if (xn != xn) xn = -1.0f;
        bool use_n = (nv < TN) && ((float)t >= (float)nv - ht);
        bool use_p = (pv >= 0) && ((float)t <= (float)pv + ht);
        float o = use_n ? xn : (use_p ? xp : x);
        xsf[(size_t)b * TN + t] = o;
    }
}

// ---------------- K2: persistent column-split GRU, L3-coherent comm ----------------
// grid 256 = 8 batch-groups x 32 col-groups; block 256 (4 waves); 1 WG/CU.
// Producer protocol is byte-for-byte the proven R0 scheme: relaxed agent-scope atomics,
// per-WG flags (padded to one line), __syncthreads drains vmcnt(0) (publish stores
// acked at coherence point) before the tid0 flag store. G16-safe.
// R7 consumer restructure (traffic-neutral -- R3 proved volume doesn't matter, R1/R6
// proved EXTRA volume hurts; this adds none):
//  - K-split waves: wave wv consumes k-slices kc ≡ wv (mod 4) (128 of 512 k-cols) and
//    computes partial sums of ALL 3 gates over them -> per-WG load volume (32 KB) and
//    MFMA count (144) unchanged.
//  - Direct global->register MFMA A-fragments: lane (frow,kgrp) loads 4 contiguous u64
//    (32 B) per slice and v_perms them in-register into hi/lo f16x8 -- the LDS h-staging
//    pass, its deinterleave, its barrier, and its bank traffic are all deleted (3->2
//    barriers/step).
//  - Each wave polls only the 8 producer flags it consumes (1 load instr, lanes 0..7).
//  - Gate partials reduced via a small LDS buffer (sPart, +18 pad -> ~2-way max).
// ABA/parity unchanged: flag t+1 from WG C implies C consumed ALL its step-t slices
// (reads precede publish in program order), so parity-p slots are dead before any
// t+2 overwrite.
__global__ __launch_bounds__(256, 1) void k_gru(
    const float* __restrict__ inp, const float* __restrict__ w_ih,
    const float* __restrict__ w_hh, const float* __restrict__ b_ih,
    const float* __restrict__ b_hh, const float* __restrict__ w_fc,
    const float* __restrict__ b_fc, const float* __restrict__ xsf,
    uint32* __restrict__ hbufP, int* __restrict__ flags, float* __restrict__ out) {
    __shared__ float sPart[3][4][16][18];   // [gate][wave][batch-row][col(+pad)]
    __shared__ float sWi0[48], sWi1[48], sBias[48];

    const int tid = threadIdx.x;
    const int gb = blockIdx.x & 7;
    const int gc = blockIdx.x >> 3;
    const int lane = tid & 63;
    const int wv   = tid >> 6;        // 0..3: k-split wave
    const int bs   = tid >> 4;        // gate-math row 0..15
    const int j    = tid & 15;
    const int bglob = gb * BSn + bs;
    const int pcol  = gc * HCn + j;
    const int frow = lane & 15;       // MFMA m (A) / n (B) index
    const int kgrp = lane >> 4;       // MFMA k-group

    if (tid < 48) {
        int gate = tid >> 4, jj = tid & 15;
        int grow = gate * HN + gc * HCn + jj;
        sWi0[tid]  = w_ih[grow * 2 + 0];
        sWi1[tid]  = w_ih[grow * 2 + 1];
        sBias[tid] = b_ih[grow] + b_hh[grow];
    }

    // one-time: weight B-fragments into VGPRs (hi + lo*2^11 split).
    // wave wv holds, for each gate g, the 4 k-slices kc = 4s+wv.
    f16x8 bfh[3][4], bfl[3][4];
#pragma unroll
    for (int g = 0; g < 3; ++g) {
        const float* wrow = w_hh + (size_t)(g * HN + gc * HCn + frow) * HN;
#pragma unroll
        for (int s = 0; s < 4; ++s) {
            const int k0 = (4 * s + wv) * 32 + kgrp * 8;
#pragma unroll
            for (int u = 0; u < 8; ++u) {
                float w = wrow[k0 + u];
                f16 hi = (f16)w;
                bfh[g][s][u] = hi;
                bfl[g][s][u] = (f16)((w - (float)hi) * 2048.0f);
            }
        }
    }
    __syncthreads();

    int* myflags = flags + gb * GCn * FLSTR;
    float h = 0.0f;

    for (int t = 0; t < TN; ++t) {
        // prefetch driving inputs (independent of sync)
        float xsv = xsf[(size_t)bglob * TN + t];
        float mkv = inp[((size_t)bglob * 3 + 2) * TN + t];
        const u64* src64 = (const u64*)(hbufP + ((size_t)(t & 1) * BN + gb * BSn) * HN);

        // 1. poll the 8 producer flags this wave consumes (lanes 0..7, one line each)
        if (lane < 8) {
            const int p = 8 * (lane >> 1) + 2 * wv + (lane & 1);
            while (__hip_atomic_load(&myflags[p * FLSTR], __ATOMIC_RELAXED,
                                     __HIP_MEMORY_SCOPE_AGENT) < t) {}
        }

        // 2. load this wave's 4 k-slices: 16 coherent u64 loads/lane-slice
        //    lane (frow,kgrp), slice kc=4s+wv: 4 contiguous u64 at frow*256+kc*16+kgrp*4
        u64 hv[4][4];
        const int rbase = frow * (HN / 2) + kgrp * 4;
#pragma unroll
        for (int s = 0; s < 4; ++s)
#pragma unroll
            for (int i = 0; i < 4; ++i)
                hv[s][i] = __hip_atomic_load(src64 + rbase + (4 * s + wv) * 16 + i,
                                             __ATOMIC_RELAXED, __HIP_MEMORY_SCOPE_AGENT);

        // 3. MFMA directly from registers: per slice, perm-deinterleave hi/lo then
        //    3 gates x 3 split-term MFMAs (loads of later slices overlap earlier MFMAs)
        f32x4 acch[3] = {{0.f,0.f,0.f,0.f},{0.f,0.f,0.f,0.f},{0.f,0.f,0.f,0.f}};
        f32x4 accl[3] = {{0.f,0.f,0.f,0.f},{0.f,0.f,0.f,0.f},{0.f,0.f,0.f,0.f}};
#pragma unroll
        for (int s = 0; s < 4; ++s) {
            u32x4 ua, ul;
#pragma unroll
            for (int i = 0; i < 4; ++i) {
                uint32 d0 = (uint32)hv[s][i], d1 = (uint32)(hv[s][i] >> 32);
                ua[i] = __builtin_amdgcn_perm(d1, d0, 0x05040100u);
                ul[i] = __builtin_amdgcn_perm(d1, d0, 0x07060302u);
            }
            f16x8 ah = __builtin_bit_cast(f16x8, ua);
            f16x8 al = __builtin_bit_cast(f16x8, ul);
#pragma unroll
            for (int g = 0; g < 3; ++g) {
                acch[g] = __builtin_amdgcn_mfma_f32_16x16x32_f16(ah, bfh[g][s], acch[g], 0, 0, 0);
                accl[g] = __builtin_amdgcn_mfma_f32_16x16x32_f16(ah, bfl[g][s], accl[g], 0, 0, 0);
                accl[g] = __builtin_amdgcn_mfma_f32_16x16x32_f16(al, bfh[g][s], accl[g], 0, 0, 0);
            }
        }
        // 4. write per-wave partials (C/D: row=(lane>>4)*4+r, col=lane&15)
#pragma unroll
        for (int g = 0; g < 3; ++g)
#pragma unroll
            for (int r = 0; r < 4; ++r)
                sPart[g][wv][kgrp * 4 + r][frow] = acch[g][r] + accl[g][r] * (1.0f / 2048.0f);
        __syncthreads();
        // 5. exact fp32 gate math (sum 4 wave-partials) + publish h_{t+1} slice
        {
            float ghr = sPart[0][0][bs][j] + sPart[0][1][bs][j]
                      + sPart[0][2][bs][j] + sPart[0][3][bs][j];
            float ghz = sPart[1][0][bs][j] + sPart[1][1][bs][j]
                      + sPart[1][2][bs][j] + sPart[1][3][bs][j];
            float ghn = sPart[2][0][bs][j] + sPart[2][1][bs][j]
                      + sPart[2][2][bs][j] + sPart[2][3][bs][j];
            float gir = xsv * sWi0[j]      + mkv * sWi1[j]      + sBias[j];
            float giz = xsv * sWi0[16 + j] + mkv * sWi1[16 + j] + sBias[16 + j];
            float gin = xsv * sWi0[32 + j] + mkv * sWi1[32 + j] + sBias[32 + j];
            float rg = 1.0f / (1.0f + __expf(-(gir + ghr)));
            float zg = 1.0f / (1.0f + __expf(-(giz + ghz)));
            float ng = tanhf(gin + rg * ghn);
            h = (1.0f - zg) * ng + zg * h;
            f16 hi = (f16)h;
            f16 lo = (f16)((h - (float)hi) * 2048.0f);
            uint32 pk = (uint32)__builtin_bit_cast(unsigned short, hi)
                      | ((uint32)__builtin_bit_cast(unsigned short, lo) << 16);
            __hip_atomic_store(&hbufP[((size_t)((t + 1) & 1) * BN + bglob) * HN + pcol], pk,
                               __ATOMIC_RELAXED, __HIP_MEMORY_SCOPE_AGENT);
        }
        __syncthreads();   // drains vmcnt(0) -> publishes acked; also fences sPart reuse
        if (tid == 0)
            __hip_atomic_store(&myflags[gc * FLSTR], t + 1, __ATOMIC_RELAXED,
                               __HIP_MEMORY_SCOPE_AGENT);
    }
    // 6. final FC: out[b] = sum_k h[b][k]*w_fc[k] + b_fc
    float part = h * w_fc[pcol];
#pragma unroll
    for (int o = 1; o < 16; o <<= 1) part += __shfl_xor(part, o, 64);
    if (j == 0) {
        if (gc == 0) part += b_fc[0];
        atomicAdd(&out[bglob], part);
    }
}

extern "C" void kernel_launch(void* const* d_in, const int* in_sizes, int n_in,
                              void* d_out, int out_size, void* d_ws, size_t ws_size,
                              hipStream_t stream) {
    const float* inp  = (const float*)d_in[0];
    const float* w_ih = (const float*)d_in[1];
    const float* w_hh = (const float*)d_in[2];
    const float* b_ih = (const float*)d_in[3];
    const float* b_hh = (const float*)d_in[4];
    const float* w_fc = (const float*)d_in[5];
    const float* b_fc = (const float*)d_in[6];
    float* out = (float*)d_out;
    char* ws = (char*)d_ws;
    int*    flags = (int*)ws;
    float*  scal  = (float*)(ws + OFF_SCAL);
    uint32* hbufP = (uint32*)(ws + OFF_HBUF);
    float*  xsf   = (float*)(ws + OFF_XSF);

    // zero: flags + scal + packed-h buf0 (= h_0 = 0); d_out (atomicAdd target)
    hipMemsetAsync(ws, 0, OFF_HBUF + BN * HN * 4, stream);
    hipMemsetAsync(d_out, 0, BN * sizeof(float), stream);
    k_prep<<<1, 256, 0, stream>>>(w_ih, scal);
    k_fill<<<BN, 64, 0, stream>>>(inp, scal, xsf);
    k_gru<<<GBn * GCn, 256, 0, stream>>>(inp, w_ih, w_hh, b_ih, b_hh, w_fc, b_fc,
                                         xsf, hbufP, flags, out);
}

// Round 9
// 3836.946 us; speedup vs baseline: 1.5794x; 1.3430x over previous
//
#include <hip/hip_runtime.h>
#include <math.h>

// Problem constants
#define BN   128      // batch
#define TN   1440     // timesteps
#define HN   512      // hidden
#define GBn  8        // batch groups
#define BSn  16       // batches per group
#define GCn  32       // column groups
#define HCn  16       // h-cols per WG
#define WST  536      // LDS row stride in f16: 268 dw == 12 mod 32 -> conflict-free b128 frag reads

using f16 = _Float16;
typedef f16   f16x8 __attribute__((ext_vector_type(8)));
typedef float f32x4 __attribute__((ext_vector_type(4)));
typedef unsigned int       uint32;
typedef unsigned long long u64;

// ws layout (bytes):
//   [0,1024)             flags[8][32] int
//   [1024,2048)          scal: [0]=half_tau, [1]=trigger
//   [2048,526336)        hbufP uint32 [2 buf][128 b][512 k]  (lo16=f16 hi, hi16=f16 lo*2048)
//   [526336,1263616)     xsf f32 [128][1440]
#define OFF_SCAL 1024
#define OFF_HBUF 2048
#define OFF_XSF  (2048 + 2 * BN * HN * 4)

// ---------------- K0: scalar prep (grads -> half_tau, trigger) ----------------
__global__ void k_prep(const float* __restrict__ w_ih, float* __restrict__ scal) {
    __shared__ float ssum[4];
    float s = 0.0f;
    for (int i = threadIdx.x; i < 3 * HN * 2; i += 256) s += w_ih[i];
    for (int o = 32; o >= 1; o >>= 1) s += __shfl_down(s, o, 64);
    if ((threadIdx.x & 63) == 0) ssum[threadIdx.x >> 6] = s;
    __syncthreads();
    if (threadIdx.x == 0) {
        float tot = ssum[0] + ssum[1] + ssum[2] + ssum[3];
        float grads = tot / 3072.0f - 1.0f;
        float tau_new = 6.0f + grads * 0.1f;
        bool trig = (tau_new >= 1.0f) && (tau_new != 6.0f);
        scal[0] = rintf(tau_new * 0.5f);   // round-half-even matches jnp.round
        scal[1] = trig ? 1.0f : 0.0f;
    }
}

// ---------------- K1: NaN-fix + belief_fill (one wave per batch row) ----------------
__global__ void k_fill(const float* __restrict__ inp, const float* __restrict__ scal,
                       float* __restrict__ xsf) {
    const int b = blockIdx.x;
    const int lane = threadIdx.x;            // 0..63
    const float ht = scal[0];
    const bool trig = scal[1] != 0.0f;
    const float* xrow = inp + (size_t)b * 3 * TN;       // channel 0 = xs
    const float* mrow = xrow + 2 * TN;                   // channel 2 = mask
    const int CH = 23;                                   // 64*23 = 1472 >= 1440
    const int start = lane * CH;

    if (!trig) {
        for (int i = 0; i < CH; ++i) {
            int t = start + i;
            if (t < TN) { float x = xrow[t]; if (x != x) x = -1.0f; xsf[(size_t)b * TN + t] = x; }
        }
        return;
    }
    int pm = -1;
#pragma unroll
    for (int i = 0; i < CH; ++i) { int t = start + i; if (t < TN && mrow[t] == 1.0f) pm = t; }
    int incl = pm;
    for (int o = 1; o < 64; o <<= 1) { int v = __shfl_up(incl, o, 64); if (lane >= o) incl = max(incl, v); }
    int pexcl = __shfl_up(incl, 1, 64); if (lane == 0) pexcl = -1;
    int nm = TN;
#pragma unroll
    for (int i = CH - 1; i >= 0; --i) { int t = start + i; if (t < TN && mrow[t] == 1.0f) nm = t; }
    int incl2 = nm;
    for (int o = 1; o < 64; o <<= 1) { int v = __shfl_down(incl2, o, 64); if (lane + o < 64) incl2 = min(incl2, v); }
    int nexcl = __shfl_down(incl2, 1, 64); if (lane == 63) nexcl = TN;
    int narr[23];
    int runn = nexcl;
#pragma unroll
    for (int i = CH - 1; i >= 0; --i) {
        int t = start + i;
        if (t < TN) { if (mrow[t] == 1.0f) runn = t; narr[i] = runn; } else narr[i] = TN;
    }
    int runp = pexcl;
#pragma unroll
    for (int i = 0; i < CH; ++i) {
        int t = start + i;
        if (t >= TN) break;
        float x = xrow[t]; if (x != x) x = -1.0f;
        if (mrow[t] == 1.0f) runp = t;
        int pv = runp, nv = narr[i];
        int pc = min(max(pv, 0), TN - 1), nc = min(max(nv, 0), TN - 1);
        float xp = xrow[pc]; if (xp != xp) xp = -1.0f;
        float xn = xrow[nc]; if (xn != xn) xn = -1.0f;
        bool use_n = (nv < TN) && ((float)t >= (float)nv - ht);
        bool use_p = (pv >= 0) && ((float)t <= (float)pv + ht);
        float o = use_n ? xn : (use_p ? xp : x);
        xsf[(size_t)b * TN + t] = o;
    }
}

// ---------------- K2: persistent column-split GRU, L3-coherent comm ----------------
// grid 256 = 8 batch-groups x 32 col-groups; block 256 (4 waves); 1 WG/CU.
// Protocol, layout, staging, poll, drain, flag: byte-identical to the proven R0
// kernel (3911us). Six rounds of experiments showed every protocol change regresses
// (extra transactions on the coherent h-buffer) or fails; R9 therefore only shortens
// the COMPUTE segment of the serial chain:
//  (a) MFMA accumulator chains split 2 -> 6 (even/odd c x {hi*hi, hi*lo, lo*hi}):
//      max dependent-MFMA depth 32 -> 8, removing ~300-500cy of dependency stall
//      between the two barriers. (+16 VGPR, occupancy unchanged at 1 WG/CU.)
//  (b) gate math: tanh via 2*sigmoid(2x)-1 and sigmoid via __fdividef+__expf
//      (v_rcp-based) -- removes the branchy libm tanhf and 3 precise-division
//      sequences (~60 VALU instrs/thread) from the serial tail. Perturbation ~1-2ulp,
//      far below the 2.44e-4 absmax floor set by the f16 hi/lo h-packing.
__global__ __launch_bounds__(256, 1) void k_gru(
    const float* __restrict__ inp, const float* __restrict__ w_ih,
    const float* __restrict__ w_hh, const float* __restrict__ b_ih,
    const float* __restrict__ b_hh, const float* __restrict__ w_fc,
    const float* __restrict__ b_fc, const float* __restrict__ xsf,
    uint32* __restrict__ hbufP, int* __restrict__ flags, float* __restrict__ out) {
    __shared__ __align__(16) f16 sHhi[BSn * WST];
    __shared__ __align__(16) f16 sHlo[BSn * WST];
    __shared__ float sGh[3][BSn][HCn + 1];
    __shared__ float sWi0[48], sWi1[48], sBias[48];

    const int tid = threadIdx.x;
    const int gb = blockIdx.x & 7;
    const int gc = blockIdx.x >> 3;
    const int lane = tid & 63;
    const int wv   = tid >> 6;
    const int bs   = tid >> 4;        // gate-math row 0..15
    const int j    = tid & 15;
    const int bglob = gb * BSn + bs;
    const int pcol  = gc * HCn + j;
    const int frow = lane & 15;       // MFMA m (A) / n (B) index
    const int kgrp = lane >> 4;       // MFMA k-group

    if (tid < 48) {
        int gate = tid >> 4, jj = tid & 15;
        int grow = gate * HN + gc * HCn + jj;
        sWi0[tid]  = w_ih[grow * 2 + 0];
        sWi1[tid]  = w_ih[grow * 2 + 1];
        sBias[tid] = b_ih[grow] + b_hh[grow];
    }

    // one-time: weight B-fragments into VGPRs (hi + lo*2^11 split)
    f16x8 bfh[16], bfl[16];
    if (wv < 3) {
        const float* wrow = w_hh + (size_t)(wv * HN + gc * HCn + frow) * HN;
#pragma unroll
        for (int c = 0; c < 16; ++c) {
            const int k0 = (c * 4 + kgrp) * 8;
#pragma unroll
            for (int u = 0; u < 8; ++u) {
                float w = wrow[k0 + u];
                f16 hi = (f16)w;
                bfh[c][u] = hi;
                bfl[c][u] = (f16)((w - (float)hi) * 2048.0f);
            }
        }
    }
    __syncthreads();

    int* myflags = flags + gb * GCn;
    const f16x8* pAhi = (const f16x8*)(sHhi + frow * WST);
    const f16x8* pAlo = (const f16x8*)(sHlo + frow * WST);
    float h = 0.0f;

    for (int t = 0; t < TN; ++t) {
        // prefetch driving inputs (independent of sync)
        float xsv = xsf[(size_t)bglob * TN + t];
        float mkv = inp[((size_t)bglob * 3 + 2) * TN + t];
        // 1. every wave polls all 32 peer flags (relaxed atomic load = L3 read, no inv)
        if (lane < GCn) {
            while (__hip_atomic_load(&myflags[lane], __ATOMIC_RELAXED, __HIP_MEMORY_SCOPE_AGENT) < t) {}
        }
        // 2. stage h_t into LDS: 16 coherent u64 loads/thread (2 packed dwords of batch row i)
        {
            const uint32* src = hbufP + ((size_t)(t & 1) * BN + gb * BSn) * HN;
            u64 hv[16];
#pragma unroll
            for (int i = 0; i < 16; ++i)
                hv[i] = __hip_atomic_load((const u64*)(src + (size_t)i * HN) + tid,
                                          __ATOMIC_RELAXED, __HIP_MEMORY_SCOPE_AGENT);
#pragma unroll
            for (int i = 0; i < 16; ++i) {
                uint32 d0 = (uint32)hv[i], d1 = (uint32)(hv[i] >> 32);
                ((uint32*)(sHhi + i * WST))[tid] = __builtin_amdgcn_perm(d1, d0, 0x05040100u);
                ((uint32*)(sHlo + i * WST))[tid] = __builtin_amdgcn_perm(d1, d0, 0x07060302u);
            }
        }
        __syncthreads();
        // 3. MFMA: wave wv computes gate tile wv (16x16), K=512, 3 split terms.
        //    Six accumulators (even/odd c x {h*h, h*l, l*h}) -> dependent-chain depth 8.
        if (wv < 3) {
            f32x4 ah0 = {0.f,0.f,0.f,0.f}, ah1 = {0.f,0.f,0.f,0.f};
            f32x4 al0 = {0.f,0.f,0.f,0.f}, al1 = {0.f,0.f,0.f,0.f};
            f32x4 bl0 = {0.f,0.f,0.f,0.f}, bl1 = {0.f,0.f,0.f,0.f};
#pragma unroll
            for (int c = 0; c < 16; c += 2) {
                f16x8 ha = pAhi[c * 4 + kgrp];
                f16x8 la = pAlo[c * 4 + kgrp];
                f16x8 hb = pAhi[(c + 1) * 4 + kgrp];
                f16x8 lb = pAlo[(c + 1) * 4 + kgrp];
                ah0 = __builtin_amdgcn_mfma_f32_16x16x32_f16(ha, bfh[c],     ah0, 0, 0, 0);
                ah1 = __builtin_amdgcn_mfma_f32_16x16x32_f16(hb, bfh[c + 1], ah1, 0, 0, 0);
                al0 = __builtin_amdgcn_mfma_f32_16x16x32_f16(ha, bfl[c],     al0, 0, 0, 0);
                al1 = __builtin_amdgcn_mfma_f32_16x16x32_f16(hb, bfl[c + 1], al1, 0, 0, 0);
                bl0 = __builtin_amdgcn_mfma_f32_16x16x32_f16(la, bfh[c],     bl0, 0, 0, 0);
                bl1 = __builtin_amdgcn_mfma_f32_16x16x32_f16(lb, bfh[c + 1], bl1, 0, 0, 0);
            }
            // C/D: row=(lane>>4)*4+r (batch), col=lane&15 (j)
#pragma unroll
            for (int r = 0; r < 4; ++r)
                sGh[wv][kgrp * 4 + r][frow] =
                    (ah0[r] + ah1[r]) + (al0[r] + al1[r] + bl0[r] + bl1[r]) * (1.0f / 2048.0f);
        }
        __syncthreads();
        // 4. fast-math gate math + publish h_{t+1} slice (write-through atomic store)
        {
            float ghr = sGh[0][bs][j], ghz = sGh[1][bs][j], ghn = sGh[2][bs][j];
            float gir = xsv * sWi0[j]      + mkv * sWi1[j]      + sBias[j];
            float giz = xsv * sWi0[16 + j] + mkv * sWi1[16 + j] + sBias[16 + j];
            float gin = xsv * sWi0[32 + j] + mkv * sWi1[32 + j] + sBias[32 + j];
            float rg = __fdividef(1.0f, 1.0f + __expf(-(gir + ghr)));
            float zg = __fdividef(1.0f, 1.0f + __expf(-(giz + ghz)));
            float xt = gin + rg * ghn;
            float ng = __fdividef(2.0f, 1.0f + __expf(-2.0f * xt)) - 1.0f;  // tanh(xt)
            h = (1.0f - zg) * ng + zg * h;
            f16 hi = (f16)h;
            f16 lo = (f16)((h - (float)hi) * 2048.0f);
            uint32 pk = (uint32)__builtin_bit_cast(unsigned short, hi)
                      | ((uint32)__builtin_bit_cast(unsigned short, lo) << 16);
            __hip_atomic_store(&hbufP[((size_t)((t + 1) & 1) * BN + bglob) * HN + pcol], pk,
                               __ATOMIC_RELAXED, __HIP_MEMORY_SCOPE_AGENT);
        }
        __syncthreads();   // compiler drains vmcnt(0) before s_barrier -> publishes acked at L3
        if (tid == 0)
            __hip_atomic_store(&myflags[gc], t + 1, __ATOMIC_RELAXED, __HIP_MEMORY_SCOPE_AGENT);
    }
    // 5. final FC: out[b] = sum_k h[b][k]*w_fc[k] + b_fc
    float part = h * w_fc[pcol];
#pragma unroll
    for (int o = 1; o < 16; o <<= 1) part += __shfl_xor(part, o, 64);
    if (j == 0) {
        if (gc == 0) part += b_fc[0];
        atomicAdd(&out[bglob], part);
    }
}

extern "C" void kernel_launch(void* const* d_in, const int* in_sizes, int n_in,
                              void* d_out, int out_size, void* d_ws, size_t ws_size,
                              hipStream_t stream) {
    const float* inp  = (const float*)d_in[0];
    const float* w_ih = (const float*)d_in[1];
    const float* w_hh = (const float*)d_in[2];
    const float* b_ih = (const float*)d_in[3];
    const float* b_hh = (const float*)d_in[4];
    const float* w_fc = (const float*)d_in[5];
    const float* b_fc = (const float*)d_in[6];
    float* out = (float*)d_out;
    char* ws = (char*)d_ws;
    int*    flags = (int*)ws;
    float*  scal  = (float*)(ws + OFF_SCAL);
    uint32* hbufP = (uint32*)(ws + OFF_HBUF);
    float*  xsf   = (float*)(ws + OFF_XSF);

    // zero: flags + scal + packed-h buf0 (= h_0 = 0); d_out (atomicAdd target)
    hipMemsetAsync(ws, 0, OFF_HBUF + BN * HN * 4, stream);
    hipMemsetAsync(d_out, 0, BN * sizeof(float), stream);
    k_prep<<<1, 256, 0, stream>>>(w_ih, scal);
    k_fill<<<BN, 64, 0, stream>>>(inp, scal, xsf);
    k_gru<<<GBn * GCn, 256, 0, stream>>>(inp, w_ih, w_hh, b_ih, b_hh, w_fc, b_fc,
                                         xsf, hbufP, flags, out);
}